// Round 9
// baseline (145.965 us; speedup 1.0000x reference)
//
#include <hip/hip_runtime.h>
#include <hip/hip_bf16.h>

// Problem constants
#define N_TOK 8192
#define INL   512
#define OUTL  512
#define NE    8
#define NI    16
#define EOFF  (OUTL * INL)   // elems per expert in wt

typedef unsigned short ushort_t;
typedef unsigned int   uint_t;
typedef short  short8  __attribute__((ext_vector_type(8)));
typedef float  floatx4 __attribute__((ext_vector_type(4)));

// ---------------- workspace layout (bytes) ----------------
#define WS_CNT    0u         // int[64] @ stride 16 ints (64B): pair = e0*8+e1
#define WS_BET    8192u      // float[4096]: bet_eff[e][d] = bet + gam*b
#define WS_SELW   32768u     // float4[8192]: {rw0*gam0, rw1*gam1, rw0, rw1}
#define WS_WT     163840u    // ushort[8*512*512] : W^T bf16 [e][d][l]
#define WS_LIST   4358144u   // int[64*8192] : token lists per pair
#define WS_XBF    6455296u   // ushort[8192*512] : x in bf16 (unscaled)
#define MAXT2     120        // bound: 56 pairs + 8192/128 tiles (M=128)

__device__ __forceinline__ ushort_t f2bf(float f) {
    uint_t b = __float_as_uint(f);
    return (ushort_t)((b + 0x7FFFu + ((b >> 16) & 1u)) >> 16);   // RNE
}
__device__ __forceinline__ uint_t pkbf(float a, float b) {
    __hip_bfloat162 h = __float22bfloat162_rn(make_float2(a, b));  // v_cvt_pk_bf16_f32
    union { __hip_bfloat162 h2; uint_t u; } cv;
    cv.h2 = h;
    return cv.u;
}
// async global->LDS DMA, 16 B per lane; LDS dest = wave-uniform base + lane*16
__device__ __forceinline__ void dma16(const ushort_t* g, ushort_t* l) {
    __builtin_amdgcn_global_load_lds(
        (const __attribute__((address_space(1))) void*)g,
        (__attribute__((address_space(3))) void*)l,
        16, 0, 0);
}

// ================= K1: fused prep + router =================
// blocks [0,512):    Wt transpose/convert  (e = bx>>6; tile = bx&63)
// blocks [512,640):  bet_eff               (e = b>>4; dBase = (b&15)*32)
// blocks [640,896):  x fp32 -> bf16 (unscaled)
// blocks [896,1408): router + pair scatter (16 tok/block; gam/rgam computed
//                    locally, identical reduction order -> bit-identical)
__global__ __launch_bounds__(256)
void k_fused(const float* __restrict__ x,
             const float* __restrict__ ins,
             const float* __restrict__ expert_w,
             const float* __restrict__ expert_b,
             const float* __restrict__ gamma_w,
             const float* __restrict__ beta_w,
             const float* __restrict__ rmod_w,
             const float* __restrict__ gate_w,
             ushort_t* __restrict__ wt,
             ushort_t* __restrict__ xbf,
             float* __restrict__ wsBet,
             float4* __restrict__ selW,
             int* __restrict__ wsCnt, int* __restrict__ wsList) {
    __shared__ __align__(16) char smem[20480];
    int bx = blockIdx.x;
    int tid = threadIdx.x;

    if (bx < 512) {   // Wt transpose/convert
        float (*tile)[65] = (float(*)[65])smem;
        int e = bx >> 6, rem = bx & 63;
        int lt = (rem >> 3) * 64, dt = (rem & 7) * 64;
        int dIdx = tid & 63, lq = tid >> 6;
        for (int i = 0; i < 16; ++i) {
            int l = lq * 16 + i;
            tile[l][dIdx] = expert_w[(e * INL + lt + l) * OUTL + dt + dIdx];
        }
        __syncthreads();
        int lIdx = tid & 63, dq = tid >> 6;
        for (int i = 0; i < 16; ++i) {
            int d = dq * 16 + i;
            wt[(e * OUTL + dt + d) * INL + lt + lIdx] = f2bf(tile[lIdx][d]);
        }
        return;
    }

    if (bx < 640) {   // bet_eff
        float* sS  = (float*)smem;          // [512]
        float* red = sS + 512;              // [256]
        float* gamS = red + 256;            // [1]
        int b2 = bx - 512;
        int e = b2 >> 4, dBase = (b2 & 15) * 32;
        for (int h = tid; h < INL; h += 256) {
            float a = 0.f;
            for (int n = 0; n < NI; ++n) a += ins[n * INL + h];
            sS[h] = a;
        }
        __syncthreads();
        if (tid < 64) {
            float g = 0.f;
            for (int j = 0; j < 8; ++j) g += sS[tid * 8 + j] * gamma_w[e * INL + tid * 8 + j];
            for (int off = 32; off >= 1; off >>= 1) g += __shfl_xor(g, off, 64);
            if (tid == 0) gamS[0] = g * (1.f / NI);
        }
        int doff = tid & 31, hq = tid >> 5;
        float a = 0.f;
        for (int j = 0; j < 64; ++j) {
            int h = hq * 64 + j;
            a += sS[h] * beta_w[(e * INL + h) * OUTL + dBase + doff];
        }
        red[tid] = a;
        __syncthreads();
        if (tid < 32) {
            float t = 0.f;
            for (int k = 0; k < 8; ++k) t += red[k * 32 + tid];
            int d = dBase + tid;
            wsBet[e * OUTL + d] = t * (1.f / NI) + gamS[0] * expert_b[e * OUTL + d];
        }
        return;
    }

    if (bx < 896) {   // x -> bf16 convert, 16384 elems each
        int b2 = bx - 640;
        const float* xp = x + (size_t)b2 * 16384;
        ushort_t* xq = xbf + (size_t)b2 * 16384;
        #pragma unroll
        for (int j = 0; j < 16; ++j) {
            int o = j * 1024 + tid * 4;
            float4 v = *(const float4*)(xp + o);
            uint2 u;
            u.x = pkbf(v.x, v.y);
            u.y = pkbf(v.z, v.w);
            *(uint2*)(xq + o) = u;
        }
        return;
    }

    {   // router + pair scatter, rb in [0, 512)
        int rb = bx - 896;
        float* sS   = (float*)smem;            // [512]
        float* pg   = sS + 512;                // [64]
        float* pr   = pg + 64;                 // [64]
        float* gam8 = pr + 64;                 // [8]
        float* rg8  = gam8 + 8;                // [8]
        int*   tokP  = (int*)(smem + 2624);    // [16]
        int*   cnt64 = tokP + 16;              // [64]
        int*   base64 = cnt64 + 64;            // [64]
        int*   pos   = base64 + 64;            // [16]
        float* gateT = (float*)(smem + 4096);  // [NE*INL] 16 KB

        // local stats (same reduction order as the old stats block)
        for (int h = tid; h < INL; h += 256) {
            float a = 0.f;
            for (int n = 0; n < NI; ++n) a += ins[n * INL + h];
            sS[h] = a;
        }
        __syncthreads();
        if (tid < 64) {
            int e = tid & 7, qq = tid >> 3;
            float g = 0.f, r = 0.f;
            for (int j = 0; j < 64; ++j) {
                int h = qq * 64 + j;
                float sv = sS[h];
                g += sv * gamma_w[e * INL + h];
                r += sv * rmod_w[h * NE + e];
            }
            pg[tid] = g; pr[tid] = r;
        }
        __syncthreads();
        if (tid < NE) {
            float g = 0.f, r = 0.f;
            for (int qq = 0; qq < 8; ++qq) { g += pg[qq * 8 + tid]; r += pr[qq * 8 + tid]; }
            gam8[tid] = g * (1.f / NI);
            rg8[tid]  = r * (1.f / NI);
        }
        for (int i = 0; i < 16; ++i) {
            int f = tid + 256 * i;
            gateT[(f & 7) * INL + (f >> 3)] = gate_w[f];
        }
        if (tid < 64) cnt64[tid] = 0;
        __syncthreads();

        int w = tid >> 6, lane = tid & 63;
        int tbase = rb * 16 + w * 4;

        for (int tt = 0; tt < 4; ++tt) {
            int t = tbase + tt;
            float2 xv[4];
            for (int i = 0; i < 4; ++i)
                xv[i] = *(const float2*)(x + (size_t)t * INL + 2 * lane + 128 * i);

            float acc[NE];
            for (int e = 0; e < NE; ++e) acc[e] = 0.f;
            for (int i = 0; i < 4; ++i) {
                int c = 2 * lane + 128 * i;
                for (int e = 0; e < NE; ++e)
                    acc[e] += xv[i].x * gateT[e * INL + c] + xv[i].y * gateT[e * INL + c + 1];
            }
            for (int e = 0; e < NE; ++e) {
                float a = acc[e];
                for (int off = 32; off >= 1; off >>= 1) a += __shfl_xor(a, off, 64);
                acc[e] = a;
            }
            float logit[NE];
            for (int e = 0; e < NE; ++e) logit[e] = acc[e] + rg8[e];

            int i0 = 0; float m0 = logit[0];
            for (int e = 1; e < NE; ++e) if (logit[e] > m0) { m0 = logit[e]; i0 = e; }
            int i1 = -1; float m1 = -3.4e38f;
            for (int e = 0; e < NE; ++e) if (e != i0 && logit[e] > m1) { m1 = logit[e]; i1 = e; }

            float S = 0.f;
            for (int e = 0; e < NE; ++e) S += expf(logit[e] - m0);
            float rw0 = 1.0f / S;
            float rw1 = expf(m1 - m0) / S;

            if (lane == 0) {
                selW[t] = make_float4(rw0 * gam8[i0], rw1 * gam8[i1], rw0, rw1);
                tokP[w * 4 + tt] = i0 * 8 + i1;
            }
        }
        __syncthreads();

        if (tid < 16) pos[tid] = atomicAdd(&cnt64[tokP[tid]], 1);
        __syncthreads();
        if (tid < 64 && cnt64[tid] > 0)
            base64[tid] = atomicAdd(wsCnt + tid * 16, cnt64[tid]);
        __syncthreads();
        if (tid < 16) {
            int p = tokP[tid];
            wsList[(size_t)p * N_TOK + base64[p] + pos[tid]] = rb * 16 + tid;
        }
    }
}

// ================= K3: pair-gather GEMM, M=128 x N=64, bf16 A, post-scale ==
// ct = bx / MAXT2, bt = bx % MAXT2 -> all 8 col-slabs of one row-tile share
// bx%8 (120 % 8 == 0) -> same XCD -> gathered A rows hit that XCD's L2.
// M=128: per kc each wave issues 32 MFMA against the same 16 ds_read_b128 /
// 16 KB staging DMA as M=64 -> wt staging traffic HALVES (~136 -> ~70 MB).
// Block-entry schedule: 64 parallel counter loads + shfl_up scan + ballot.
__global__ __launch_bounds__(256, 4)
void k_gemmp(const ushort_t* __restrict__ xbf, const ushort_t* __restrict__ wt,
             const int* __restrict__ wsCnt, const int* __restrict__ wsList,
             const float4* __restrict__ selW, const float* __restrict__ wsBet,
             float* __restrict__ out) {
    int bx = blockIdx.x;
    int ct = bx / MAXT2;               // col slab: ct*64..+64
    int bt = bx % MAXT2;               // row-tile index (same XCD across ct)
    int tid = threadIdx.x;

    __shared__ int sWord;
    if (tid < 64) {
        int cnt = wsCnt[tid * 16];
        int ti = (cnt + 127) >> 7;
        int incl = ti;
        #pragma unroll
        for (int off = 1; off < 64; off <<= 1) {
            int v = __shfl_up(incl, off, 64);
            if ((tid & 63) >= off) incl += v;
        }
        int base = incl - ti;
        int hit = (bt >= base) && (bt < incl);
        unsigned long long m = __ballot(hit);
        int word = -1;
        if (m) {
            int src = __ffsll((unsigned long long)m) - 1;
            int b2 = __shfl(base, src, 64);
            int c2 = __shfl(cnt, src, 64);
            word = src | ((bt - b2) << 6) | (c2 << 14);
        }
        if (tid == 0) sWord = word;
    }
    __syncthreads();
    int s = sWord;
    if (s < 0) return;                 // surplus block
    int li = s & 63, lt = (s >> 6) & 255, cntE = s >> 14;
    int e0 = li >> 3, e1 = li & 7;
    const int* listE = wsList + (size_t)li * N_TOK;

    __shared__ ushort_t Blds[2][2][64 * 64];   // [buf][expert], 32 KB total

    int wid = tid >> 6, lane = tid & 63;
    int wm = wid * 32;                 // wave's 32-row slice (2 row-frags)
    int mrow = lane & 15, laneq = lane >> 4, q8 = laneq * 8, qr = laneq * 4;

    // gathered A rows (unscaled bf16), one per row-frag
    const ushort_t* arowp[2];
    #pragma unroll
    for (int rf = 0; rf < 2; ++rf) {
        int idx = lt * 128 + wm + rf * 16 + mrow;
        int tok = 0;
        if (idx < cntE) tok = listE[idx];
        arowp[rf] = xbf + (size_t)tok * INL + q8;
    }

    // B staging (per expert panel, proven rotate swizzle):
    // chunk c -> col=c>>3, kslot=c&7, src kgrp=(kslot-col)&7
    int c0 = tid;
    int col0 = c0 >> 3, kg0 = ((c0 & 7) - col0) & 7;
    const ushort_t* pB = wt + (size_t)e0 * EOFF + (size_t)(ct * 64 + col0) * INL + kg0 * 8;
    ptrdiff_t dE = (ptrdiff_t)(e1 - e0) * EOFF;
    ushort_t* ldsA = &Blds[0][0][0] + wid * 512;   // wave-uniform chunk region

    // fragment read swizzle
    int fcol[4], frot0[4];
    for (int nt = 0; nt < 4; ++nt) {
        fcol[nt] = nt * 16 + mrow;
        frot0[nt] = (laneq + fcol[nt]) & 7;
    }

    floatx4 acc[2][2][4];              // [expert][rf][nt], scaled at epilogue
    #pragma unroll
    for (int e = 0; e < 2; ++e)
        for (int rf = 0; rf < 2; ++rf)
            for (int nt = 0; nt < 4; ++nt)
                acc[e][rf][nt] = (floatx4){0.f, 0.f, 0.f, 0.f};

    // prologue: DMA kc=0 (both experts) into buf0 + A regs for kc=0, drain
    dma16(pB,                 ldsA);
    dma16(pB + 32 * INL,      ldsA + 2048);
    dma16(pB + dE,            ldsA + 4096);
    dma16(pB + dE + 32 * INL, ldsA + 6144);
    short8 ca[2][2];                   // [rf][ks]
    #pragma unroll
    for (int rf = 0; rf < 2; ++rf) {
        ca[rf][0] = *(const short8*)(arowp[rf]);
        ca[rf][1] = *(const short8*)(arowp[rf] + 32);
    }
    __syncthreads();

    #pragma unroll
    for (int kc = 0; kc < 8; ++kc) {
        int buf = kc & 1;
        short8 na[2][2];
        // issue DMA + A prefetch for next kc (fly under this kc's compute;
        // the end-of-kc barrier's vmcnt(0) completes them)
        if (kc < 7) {
            const ushort_t* p = pB + (kc + 1) * 64;
            ushort_t* l = ldsA + (buf ^ 1) * 8192;
            dma16(p,                 l);
            dma16(p + 32 * INL,      l + 2048);
            dma16(p + dE,            l + 4096);
            dma16(p + dE + 32 * INL, l + 6144);
            #pragma unroll
            for (int rf = 0; rf < 2; ++rf) {
                const ushort_t* ap = arowp[rf] + (kc + 1) * 64;
                na[rf][0] = *(const short8*)(ap);
                na[rf][1] = *(const short8*)(ap + 32);
            }
        }

        const ushort_t* Bb = &Blds[buf][0][0];
        #pragma unroll
        for (int e = 0; e < 2; ++e) {
            const ushort_t* B = Bb + e * 4096;
            short8 bf[4][2];
            #pragma unroll
            for (int nt = 0; nt < 4; ++nt) {
                int cb = fcol[nt] * 64;
                bf[nt][0] = *(const short8*)&B[cb + frot0[nt] * 8];
                bf[nt][1] = *(const short8*)&B[cb + ((frot0[nt] + 4) & 7) * 8];
            }
            #pragma unroll
            for (int rf = 0; rf < 2; ++rf)
                for (int nt = 0; nt < 4; ++nt) {
                    acc[e][rf][nt] = __builtin_amdgcn_mfma_f32_16x16x32_bf16(
                        ca[rf][0], bf[nt][0], acc[e][rf][nt], 0, 0, 0);
                    acc[e][rf][nt] = __builtin_amdgcn_mfma_f32_16x16x32_bf16(
                        ca[rf][1], bf[nt][1], acc[e][rf][nt], 0, 0, 0);
                }
        }
        __syncthreads();   // drain next-DMA + A prefetch, release buf readers
        if (kc < 7) {
            #pragma unroll
            for (int rf = 0; rf < 2; ++rf) {
                ca[rf][0] = na[rf][0];
                ca[rf][1] = na[rf][1];
            }
        }
    }

    // epilogue: out = w0*acc0 + w1*acc1 + rw0*bet_eff[e0] + rw1*bet_eff[e1]
    #pragma unroll
    for (int rf = 0; rf < 2; ++rf)
        for (int ri = 0; ri < 4; ++ri) {
            int idx2 = lt * 128 + wm + rf * 16 + qr + ri;
            if (idx2 >= cntE) continue;
            int tok2 = listE[idx2];
            float4 w4 = selW[tok2];
            float* op = out + (size_t)tok2 * OUTL + ct * 64;
            #pragma unroll
            for (int nt = 0; nt < 4; ++nt) {
                int col = ct * 64 + nt * 16 + mrow;
                float bet = w4.z * wsBet[e0 * OUTL + col] + w4.w * wsBet[e1 * OUTL + col];
                op[nt * 16 + mrow] = w4.x * acc[0][rf][nt][ri] + w4.y * acc[1][rf][nt][ri] + bet;
            }
        }
}

extern "C" void kernel_launch(void* const* d_in, const int* in_sizes, int n_in,
                              void* d_out, int out_size, void* d_ws, size_t ws_size,
                              hipStream_t stream) {
    const float* x        = (const float*)d_in[0];
    const float* ins      = (const float*)d_in[1];
    const float* gate_w   = (const float*)d_in[2];
    const float* expert_w = (const float*)d_in[3];
    const float* expert_b = (const float*)d_in[4];
    const float* gamma_w  = (const float*)d_in[5];
    const float* beta_w   = (const float*)d_in[6];
    const float* rmod_w   = (const float*)d_in[7];
    float* out = (float*)d_out;

    char* ws = (char*)d_ws;
    int*      wsCnt  = (int*)(ws + WS_CNT);
    float*    wsBet  = (float*)(ws + WS_BET);
    float4*   selW   = (float4*)(ws + WS_SELW);
    ushort_t* wt     = (ushort_t*)(ws + WS_WT);
    int*      wsList = (int*)(ws + WS_LIST);
    ushort_t* xbf    = (ushort_t*)(ws + WS_XBF);

    hipMemsetAsync(wsCnt, 0, 4096, stream);   // zero 64 padded pair counters
    k_fused<<<1408, 256, 0, stream>>>(x, ins, expert_w, expert_b,
                                      gamma_w, beta_w, rmod_w, gate_w,
                                      wt, xbf, wsBet, selW, wsCnt, wsList);
    k_gemmp<<<MAXT2 * 8, 256, 0, stream>>>(xbf, wt, wsCnt, wsList,
                                           selW, wsBet, out);
}

// Round 11
// 130.553 us; speedup vs baseline: 1.1181x; 1.1181x over previous
//
#include <hip/hip_runtime.h>
#include <hip/hip_bf16.h>

// Problem constants
#define N_TOK 8192
#define INL   512
#define OUTL  512
#define NE    8
#define NI    16
#define EOFF  (OUTL * INL)   // elems per expert in wt

typedef unsigned short ushort_t;
typedef unsigned int   uint_t;
typedef short  short8  __attribute__((ext_vector_type(8)));
typedef float  floatx4 __attribute__((ext_vector_type(4)));

// ---------------- workspace layout (bytes) ----------------
#define WS_CNT    0u         // int[64] @ stride 16 ints (64B): pair = e0*8+e1
#define WS_BET    8192u      // float[4096]: bet_eff[e][d] = bet + gam*b
#define WS_SELW   32768u     // float4[8192]: {rw0*gam0, rw1*gam1, rw0, rw1}
#define WS_WT     163840u    // ushort[8*512*512] : W^T bf16 [e][d][l]
#define WS_LIST   4358144u   // int[64*8192] : token lists per pair
#define WS_XBF    6455296u   // ushort[8192*512] : x in bf16 (unscaled)
#define WS_GAM    4096u      // float[8] : gam[e]
#define WS_RGAM   4352u      // float[8] : router_gamma[e]
#define MAXTP     184        // bound: 56 pairs + 8192/64 tiles (M=64)

__device__ __forceinline__ ushort_t f2bf(float f) {
    uint_t b = __float_as_uint(f);
    return (ushort_t)((b + 0x7FFFu + ((b >> 16) & 1u)) >> 16);   // RNE
}
__device__ __forceinline__ uint_t pkbf(float a, float b) {
    __hip_bfloat162 h = __float22bfloat162_rn(make_float2(a, b));  // v_cvt_pk_bf16_f32
    union { __hip_bfloat162 h2; uint_t u; } cv;
    cv.h2 = h;
    return cv.u;
}
// async global->LDS DMA, 16 B per lane; LDS dest = wave-uniform base + lane*16
__device__ __forceinline__ void dma16(const ushort_t* g, ushort_t* l) {
    __builtin_amdgcn_global_load_lds(
        (const __attribute__((address_space(1))) void*)g,
        (__attribute__((address_space(3))) void*)l,
        16, 0, 0);
}

// ================= K1: fused prep =================
// blocks [0,512):   Wt transpose/convert  (e = bx>>6; tile = bx&63)
// blocks [512,640): bet_eff               (e = b>>4; dBase = (b&15)*32)
// block  640:       stats -> wsGam, wsRgam; zero pair counters
// blocks [641,897): x fp32 -> bf16 (unscaled)
__global__ __launch_bounds__(256)
void k_prep(const float* __restrict__ x,
            const float* __restrict__ ins,
            const float* __restrict__ expert_w,
            const float* __restrict__ expert_b,
            const float* __restrict__ gamma_w,
            const float* __restrict__ beta_w,
            const float* __restrict__ rmod_w,
            ushort_t* __restrict__ wt,
            ushort_t* __restrict__ xbf,
            float* __restrict__ wsBet,
            float* __restrict__ wsGam, float* __restrict__ wsRgam,
            int* __restrict__ wsCnt) {
    __shared__ __align__(16) char smem[17152];
    int bx = blockIdx.x;
    int tid = threadIdx.x;

    if (bx < 512) {
        float (*tile)[65] = (float(*)[65])smem;
        int e = bx >> 6, rem = bx & 63;
        int lt = (rem >> 3) * 64, dt = (rem & 7) * 64;
        int dIdx = tid & 63, lq = tid >> 6;
        for (int i = 0; i < 16; ++i) {
            int l = lq * 16 + i;
            tile[l][dIdx] = expert_w[(e * INL + lt + l) * OUTL + dt + dIdx];
        }
        __syncthreads();
        int lIdx = tid & 63, dq = tid >> 6;
        for (int i = 0; i < 16; ++i) {
            int d = dq * 16 + i;
            wt[(e * OUTL + dt + d) * INL + lt + lIdx] = f2bf(tile[lIdx][d]);
        }
        return;
    }

    if (bx < 640) {
        float* sS  = (float*)smem;          // [512]
        float* red = sS + 512;              // [256]
        float* gamS = red + 256;            // [1]
        int b2 = bx - 512;
        int e = b2 >> 4, dBase = (b2 & 15) * 32;
        for (int h = tid; h < INL; h += 256) {
            float a = 0.f;
            for (int n = 0; n < NI; ++n) a += ins[n * INL + h];
            sS[h] = a;
        }
        __syncthreads();
        if (tid < 64) {
            float g = 0.f;
            for (int j = 0; j < 8; ++j) g += sS[tid * 8 + j] * gamma_w[e * INL + tid * 8 + j];
            for (int off = 32; off >= 1; off >>= 1) g += __shfl_xor(g, off, 64);
            if (tid == 0) gamS[0] = g * (1.f / NI);
        }
        int doff = tid & 31, hq = tid >> 5;
        float a = 0.f;
        for (int j = 0; j < 64; ++j) {
            int h = hq * 64 + j;
            a += sS[h] * beta_w[(e * INL + h) * OUTL + dBase + doff];
        }
        red[tid] = a;
        __syncthreads();
        if (tid < 32) {
            float t = 0.f;
            for (int k = 0; k < 8; ++k) t += red[k * 32 + tid];
            int d = dBase + tid;
            wsBet[e * OUTL + d] = t * (1.f / NI) + gamS[0] * expert_b[e * OUTL + d];
        }
        return;
    }

    if (bx == 640) {   // stats
        if (tid < 64) wsCnt[tid * 16] = 0;   // zero pair counters for k_route
        float* sS = (float*)smem;           // [512]
        float* pg = sS + 512;               // [64]
        float* pr = pg + 64;                // [64]
        for (int h = tid; h < INL; h += 256) {
            float a = 0.f;
            for (int n = 0; n < NI; ++n) a += ins[n * INL + h];
            sS[h] = a;
        }
        __syncthreads();
        if (tid < 64) {
            int e = tid & 7, qq = tid >> 3;
            float g = 0.f, r = 0.f;
            for (int j = 0; j < 64; ++j) {
                int h = qq * 64 + j;
                float sv = sS[h];
                g += sv * gamma_w[e * INL + h];
                r += sv * rmod_w[h * NE + e];
            }
            pg[tid] = g; pr[tid] = r;
        }
        __syncthreads();
        if (tid < NE) {
            float g = 0.f, r = 0.f;
            for (int qq = 0; qq < 8; ++qq) { g += pg[qq * 8 + tid]; r += pr[qq * 8 + tid]; }
            wsGam[tid]  = g * (1.f / NI);
            wsRgam[tid] = r * (1.f / NI);
        }
        return;
    }

    {   // x -> bf16 convert, blocks [641, 897): 16384 elems each
        int b2 = bx - 641;
        const float* xp = x + (size_t)b2 * 16384;
        ushort_t* xq = xbf + (size_t)b2 * 16384;
        #pragma unroll
        for (int j = 0; j < 16; ++j) {
            int o = j * 1024 + tid * 4;
            float4 v = *(const float4*)(xp + o);
            uint2 u;
            u.x = pkbf(v.x, v.y);
            u.y = pkbf(v.z, v.w);
            *(uint2*)(xq + o) = u;
        }
    }
}

// ================= K2: router + pair scatter (512 blocks, 16 tok/block) ====
__global__ __launch_bounds__(256)
void k_route(const float* __restrict__ x,
             const float* __restrict__ gate_w,
             const float* __restrict__ wsGam,
             const float* __restrict__ wsRgam,
             float4* __restrict__ selW,
             int* __restrict__ wsCnt, int* __restrict__ wsList) {
    __shared__ float gateT[NE * INL];   // 16 KB, [e][l]
    __shared__ int tokP[16];
    __shared__ int cnt64[64], base64[64], pos[16];

    int tid = threadIdx.x;
    for (int i = 0; i < 16; ++i) {
        int f = tid + 256 * i;
        gateT[(f & 7) * INL + (f >> 3)] = gate_w[f];
    }
    if (tid < 64) cnt64[tid] = 0;
    __syncthreads();

    int w = tid >> 6, lane = tid & 63;
    int tbase = blockIdx.x * 16 + w * 4;

    for (int tt = 0; tt < 4; ++tt) {
        int t = tbase + tt;
        float2 xv[4];
        for (int i = 0; i < 4; ++i)
            xv[i] = *(const float2*)(x + (size_t)t * INL + 2 * lane + 128 * i);

        float acc[NE];
        for (int e = 0; e < NE; ++e) acc[e] = 0.f;
        for (int i = 0; i < 4; ++i) {
            int c = 2 * lane + 128 * i;
            for (int e = 0; e < NE; ++e)
                acc[e] += xv[i].x * gateT[e * INL + c] + xv[i].y * gateT[e * INL + c + 1];
        }
        for (int e = 0; e < NE; ++e) {
            float a = acc[e];
            for (int off = 32; off >= 1; off >>= 1) a += __shfl_xor(a, off, 64);
            acc[e] = a;
        }
        float logit[NE];
        for (int e = 0; e < NE; ++e) logit[e] = acc[e] + wsRgam[e];

        int i0 = 0; float m0 = logit[0];
        for (int e = 1; e < NE; ++e) if (logit[e] > m0) { m0 = logit[e]; i0 = e; }
        int i1 = -1; float m1 = -3.4e38f;
        for (int e = 0; e < NE; ++e) if (e != i0 && logit[e] > m1) { m1 = logit[e]; i1 = e; }

        float S = 0.f;
        for (int e = 0; e < NE; ++e) S += expf(logit[e] - m0);
        float rw0 = 1.0f / S;
        float rw1 = expf(m1 - m0) / S;

        if (lane == 0) {
            selW[t] = make_float4(rw0 * wsGam[i0], rw1 * wsGam[i1], rw0, rw1);
            tokP[w * 4 + tt] = i0 * 8 + i1;
        }
    }
    __syncthreads();

    if (tid < 16) pos[tid] = atomicAdd(&cnt64[tokP[tid]], 1);
    __syncthreads();
    if (tid < 64 && cnt64[tid] > 0)
        base64[tid] = atomicAdd(wsCnt + tid * 16, cnt64[tid]);
    __syncthreads();
    if (tid < 16) {
        int p = tokP[tid];
        wsList[(size_t)p * N_TOK + base64[p] + pos[tid]] = blockIdx.x * 16 + tid;
    }
}

// ================= K3: pair-gather GEMM, M=64 x N=64, bf16 A, post-scale ===
// ct = bx / MAXTP, bt = bx % MAXTP  ->  all 8 col-slabs of one row-tile share
// bx%8 (184 % 8 == 0) -> same XCD -> gathered A rows hit that XCD's L2.
// Block-entry schedule inlined: 64 PARALLEL counter loads + shfl_up scan +
// ballot bin-lookup (one memory round-trip; replaces the k_sched launch).
__global__ __launch_bounds__(256, 4)
void k_gemmp(const ushort_t* __restrict__ xbf, const ushort_t* __restrict__ wt,
             const int* __restrict__ wsCnt, const int* __restrict__ wsList,
             const float4* __restrict__ selW, const float* __restrict__ wsBet,
             float* __restrict__ out) {
    int bx = blockIdx.x;
    int ct = bx / MAXTP;               // col slab: ct*64..+64
    int bt = bx % MAXTP;               // row-tile index (same XCD across ct)
    int tid = threadIdx.x;

    __shared__ int sWord;
    if (tid < 64) {
        int cnt = wsCnt[tid * 16];
        int ti = (cnt + 63) >> 6;
        int incl = ti;
        #pragma unroll
        for (int off = 1; off < 64; off <<= 1) {
            int v = __shfl_up(incl, off, 64);
            if ((tid & 63) >= off) incl += v;
        }
        int base = incl - ti;
        int hit = (bt >= base) && (bt < incl);
        unsigned long long m = __ballot(hit);
        int word = -1;
        if (m) {
            int src = __ffsll((unsigned long long)m) - 1;
            int b2 = __shfl(base, src, 64);
            int c2 = __shfl(cnt, src, 64);
            word = src | ((bt - b2) << 6) | (c2 << 14);
        }
        if (tid == 0) sWord = word;
    }
    __syncthreads();
    int s = sWord;
    if (s < 0) return;                 // surplus block
    int li = s & 63, lt = (s >> 6) & 255, cntE = s >> 14;
    int e0 = li >> 3, e1 = li & 7;
    const int* listE = wsList + (size_t)li * N_TOK;

    __shared__ ushort_t Blds[2][2][64 * 64];   // [buf][expert], 32 KB total

    int wid = tid >> 6, lane = tid & 63;
    int wm = wid * 16;                 // wave's 16-row slice
    int mrow = lane & 15, laneq = lane >> 4, q8 = laneq * 8, qr = laneq * 4;

    // gathered A row (unscaled bf16)
    int idx = lt * 64 + wm + mrow;
    int tok = 0;
    if (idx < cntE) tok = listE[idx];
    const ushort_t* arowp = xbf + (size_t)tok * INL + q8;

    // B staging (per expert panel, proven rotate swizzle):
    // chunk c -> col=c>>3, kslot=c&7, src kgrp=(kslot-col)&7
    int c0 = tid;
    int col0 = c0 >> 3, kg0 = ((c0 & 7) - col0) & 7;
    const ushort_t* pB = wt + (size_t)e0 * EOFF + (size_t)(ct * 64 + col0) * INL + kg0 * 8;
    ptrdiff_t dE = (ptrdiff_t)(e1 - e0) * EOFF;
    ushort_t* ldsA = &Blds[0][0][0] + wid * 512;   // wave-uniform chunk region

    // fragment read swizzle
    int fcol[4], frot0[4];
    for (int nt = 0; nt < 4; ++nt) {
        fcol[nt] = nt * 16 + mrow;
        frot0[nt] = (laneq + fcol[nt]) & 7;
    }

    floatx4 acc[2][4];                 // [expert][nt], scaled at epilogue
    #pragma unroll
    for (int e = 0; e < 2; ++e)
        for (int nt = 0; nt < 4; ++nt) acc[e][nt] = (floatx4){0.f, 0.f, 0.f, 0.f};

    // prologue: DMA kc=0 (both experts) into buf0 + A regs for kc=0, drain
    dma16(pB,                 ldsA);
    dma16(pB + 32 * INL,      ldsA + 2048);
    dma16(pB + dE,            ldsA + 4096);
    dma16(pB + dE + 32 * INL, ldsA + 6144);
    short8 ca0 = *(const short8*)(arowp);
    short8 ca1 = *(const short8*)(arowp + 32);
    __syncthreads();

    #pragma unroll
    for (int kc = 0; kc < 8; ++kc) {
        int buf = kc & 1;
        short8 na0, na1;
        // issue DMA + A prefetch for next kc (fly under this kc's compute;
        // the end-of-kc barrier's vmcnt(0) completes them)
        if (kc < 7) {
            const ushort_t* p = pB + (kc + 1) * 64;
            ushort_t* l = ldsA + (buf ^ 1) * 8192;
            dma16(p,                 l);
            dma16(p + 32 * INL,      l + 2048);
            dma16(p + dE,            l + 4096);
            dma16(p + dE + 32 * INL, l + 6144);
            const ushort_t* ap = arowp + (kc + 1) * 64;
            na0 = *(const short8*)(ap);
            na1 = *(const short8*)(ap + 32);
        }

        const ushort_t* Bb = &Blds[buf][0][0];
        #pragma unroll
        for (int e = 0; e < 2; ++e) {
            const ushort_t* B = Bb + e * 4096;
            short8 bf[4][2];
            #pragma unroll
            for (int nt = 0; nt < 4; ++nt) {
                int cb = fcol[nt] * 64;
                bf[nt][0] = *(const short8*)&B[cb + frot0[nt] * 8];
                bf[nt][1] = *(const short8*)&B[cb + ((frot0[nt] + 4) & 7) * 8];
            }
            #pragma unroll
            for (int nt = 0; nt < 4; ++nt) {
                acc[e][nt] = __builtin_amdgcn_mfma_f32_16x16x32_bf16(
                    ca0, bf[nt][0], acc[e][nt], 0, 0, 0);
                acc[e][nt] = __builtin_amdgcn_mfma_f32_16x16x32_bf16(
                    ca1, bf[nt][1], acc[e][nt], 0, 0, 0);
            }
        }
        __syncthreads();   // drain next-DMA + A prefetch, release buf readers
        if (kc < 7) { ca0 = na0; ca1 = na1; }
    }

    // epilogue: out = w0*acc0 + w1*acc1 + rw0*bet_eff[e0] + rw1*bet_eff[e1]
    #pragma unroll
    for (int ri = 0; ri < 4; ++ri) {
        int idx2 = lt * 64 + wm + qr + ri;
        if (idx2 >= cntE) continue;
        int tok2 = listE[idx2];
        float4 w4 = selW[tok2];
        float* op = out + (size_t)tok2 * OUTL + ct * 64;
        #pragma unroll
        for (int nt = 0; nt < 4; ++nt) {
            int col = ct * 64 + nt * 16 + mrow;
            float bet = w4.z * wsBet[e0 * OUTL + col] + w4.w * wsBet[e1 * OUTL + col];
            op[nt * 16 + mrow] = w4.x * acc[0][nt][ri] + w4.y * acc[1][nt][ri] + bet;
        }
    }
}

extern "C" void kernel_launch(void* const* d_in, const int* in_sizes, int n_in,
                              void* d_out, int out_size, void* d_ws, size_t ws_size,
                              hipStream_t stream) {
    const float* x        = (const float*)d_in[0];
    const float* ins      = (const float*)d_in[1];
    const float* gate_w   = (const float*)d_in[2];
    const float* expert_w = (const float*)d_in[3];
    const float* expert_b = (const float*)d_in[4];
    const float* gamma_w  = (const float*)d_in[5];
    const float* beta_w   = (const float*)d_in[6];
    const float* rmod_w   = (const float*)d_in[7];
    float* out = (float*)d_out;

    char* ws = (char*)d_ws;
    int*      wsCnt  = (int*)(ws + WS_CNT);
    float*    wsGam  = (float*)(ws + WS_GAM);
    float*    wsRgam = (float*)(ws + WS_RGAM);
    float*    wsBet  = (float*)(ws + WS_BET);
    float4*   selW   = (float4*)(ws + WS_SELW);
    ushort_t* wt     = (ushort_t*)(ws + WS_WT);
    int*      wsList = (int*)(ws + WS_LIST);
    ushort_t* xbf    = (ushort_t*)(ws + WS_XBF);

    k_prep<<<897, 256, 0, stream>>>(x, ins, expert_w, expert_b,
                                    gamma_w, beta_w, rmod_w,
                                    wt, xbf, wsBet, wsGam, wsRgam, wsCnt);
    k_route<<<N_TOK / 16, 256, 0, stream>>>(x, gate_w, wsGam, wsRgam,
                                            selW, wsCnt, wsList);
    k_gemmp<<<MAXTP * 8, 256, 0, stream>>>(xbf, wt, wsCnt, wsList,
                                           selW, wsBet, out);
}